// Round 6
// baseline (571.226 us; speedup 1.0000x reference)
//
#include <hip/hip_runtime.h>
#include <hip/hip_bf16.h>

typedef float f32x4 __attribute__((ext_vector_type(4)));

#define BATCH 32
#define S_LEN 4095
#define SEQ   4096
#define E_DIM 1024
#define NH    16
#define HD    64

__device__ __forceinline__ void ntstore4(float* p, f32x4 v) {
    __builtin_nontemporal_store(v, (f32x4*)p);
}

// -------- kernel 0: last-valid index + fused mask/bias per batch --------
__global__ __launch_bounds__(256) void prep_kernel(const int* __restrict__ mask,
                                                   const float* __restrict__ bias,
                                                   int* __restrict__ lastbuf,
                                                   float* __restrict__ mbias) {
    int b = blockIdx.x;
    int t = threadIdx.x;
    int best = -1;
    for (int s = t; s < SEQ; s += 256) {
        int mv = mask[b * SEQ + s];
        mbias[b * SEQ + s] = mv ? bias[s] : -1.0e9f;
        if (mv) best = max(best, s);
    }
    __shared__ int red[256];
    red[t] = best;
    __syncthreads();
    for (int o = 128; o > 0; o >>= 1) {
        if (t < o) red[t] = max(red[t], red[t + o]);
        __syncthreads();
    }
    if (t == 0) lastbuf[b] = (red[0] < 0) ? (SEQ - 1) : red[0];
}

// -------- kernel 1: qkv = h @ c_attn_w + c_attn_b, 4-way k-sliced --------
__global__ __launch_bounds__(256) void qkv_kernel(const float* __restrict__ hs,
                                                  const float* __restrict__ W,
                                                  const float* __restrict__ bias,
                                                  float* __restrict__ qkv) {
    const int b = blockIdx.y;
    const int jj = threadIdx.x & 63;
    const int j = blockIdx.x * 64 + jj;
    const int ksl = threadIdx.x >> 6;
    __shared__ float h[E_DIM];
    for (int i = threadIdx.x; i < E_DIM; i += 256) h[i] = hs[b * E_DIM + i];
    __syncthreads();
    float acc = 0.f;
    const int k0 = ksl * 256;
    #pragma unroll 8
    for (int k = k0; k < k0 + 256; ++k) acc = fmaf(h[k], W[(size_t)k * 3072 + j], acc);
    __shared__ float red[4][64];
    red[ksl][jj] = acc;
    __syncthreads();
    if (ksl == 0)
        qkv[b * 3072 + j] = acc + red[1][jj] + red[2][jj] + red[3][jj] + bias[j];
}

// -------- kernel 2a: K-phase — interleaved-row cache-append K + exp-weights --------
// block c of batch b owns rows s = 8c + 512i + u  (i,u in 0..7)
__global__ __launch_bounds__(256) void attn_k_kernel(
    const float* __restrict__ kcache, const float* __restrict__ mbias,
    const float* __restrict__ qkv, const int* __restrict__ lastbuf,
    float* __restrict__ newk, float* __restrict__ wts) {
    const int c = blockIdx.x;       // 0..63
    const int b = blockIdx.y;
    const int t = threadIdx.x;
    const int wave = t >> 6;
    const int lane = t & 63;
    const int head = wave * 4 + (lane >> 4);
    const int lig = lane & 15;
    const int col = head * HD + lig * 4;
    const int last = lastbuf[b];

    const f32x4 q4 = *(const f32x4*)(qkv + b * 3072 + col);
    const f32x4 kn4 = *(const f32x4*)(qkv + b * 3072 + 1024 + col);
    const float* kb = kcache + (size_t)b * S_LEN * E_DIM;
    float* nkb = newk + (size_t)b * SEQ * E_DIM;
    const float* mbb = mbias + b * SEQ;

    __shared__ float sc[NH][64];
    // block contains `last` iff ((last>>3)&63)==c ; contains s=4095 iff c==63
    const bool clean = (((last >> 3) & 63) != c) && (c != 63);

    if (clean) {
        for (int i = 0; i < 8; ++i) {
            const int sb = 8 * c + 512 * i;
            #pragma unroll
            for (int g = 0; g < 8; g += 4) {
                f32x4 kk[4];
                #pragma unroll
                for (int u = 0; u < 4; ++u)
                    kk[u] = *(const f32x4*)(kb + (size_t)(sb + g + u) * E_DIM + col);
                #pragma unroll
                for (int u = 0; u < 4; ++u)
                    ntstore4(nkb + (size_t)(sb + g + u) * E_DIM + col, kk[u]);
                #pragma unroll
                for (int u = 0; u < 4; ++u) {
                    float p = kk[u][0] * q4[0] + kk[u][1] * q4[1] + kk[u][2] * q4[2] + kk[u][3] * q4[3];
                    p += __shfl_xor(p, 1);
                    p += __shfl_xor(p, 2);
                    p += __shfl_xor(p, 4);
                    p += __shfl_xor(p, 8);
                    if (lig == 0)
                        sc[head][i * 8 + g + u] = __expf(fmaf(p, 0.125f, mbb[sb + g + u]));
                }
            }
        }
    } else {
        for (int i = 0; i < 8; ++i) {
            #pragma unroll
            for (int u = 0; u < 8; ++u) {
                const int s = 8 * c + 512 * i + u;
                f32x4 kk;
                if (s == last) kk = kn4;
                else if (s < S_LEN) kk = *(const f32x4*)(kb + (size_t)s * E_DIM + col);
                else kk = (f32x4){0.f, 0.f, 0.f, 0.f};
                ntstore4(nkb + (size_t)s * E_DIM + col, kk);
                float p = kk[0] * q4[0] + kk[1] * q4[1] + kk[2] * q4[2] + kk[3] * q4[3];
                p += __shfl_xor(p, 1);
                p += __shfl_xor(p, 2);
                p += __shfl_xor(p, 4);
                p += __shfl_xor(p, 8);
                if (lig == 0)
                    sc[head][i * 8 + u] = __expf(fmaf(p, 0.125f, mbb[s]));
            }
        }
    }
    __syncthreads();
    // block-private contiguous weight layout: wts[(b*64+c)*1024 + h*64 + rowidx]
    float* wblk = wts + (size_t)(b * 64 + c) * (NH * 64);
    for (int idx = t; idx < NH * 64; idx += 256)
        wblk[idx] = sc[idx >> 6][idx & 63];
}

// -------- kernel 2b: V-phase — interleaved-row cache-append V + weighted accumulate --------
__global__ __launch_bounds__(256) void attn_v_kernel(
    const float* __restrict__ vcache, const float* __restrict__ wts,
    const float* __restrict__ qkv, const int* __restrict__ lastbuf,
    float* __restrict__ newv, float* __restrict__ pl, float* __restrict__ pctx) {
    const int c = blockIdx.x;
    const int b = blockIdx.y;
    const int t = threadIdx.x;
    const int wave = t >> 6;
    const int lane = t & 63;
    const int head = wave * 4 + (lane >> 4);
    const int lig = lane & 15;
    const int col = head * HD + lig * 4;
    const int last = lastbuf[b];

    const f32x4 vn4 = *(const f32x4*)(qkv + b * 3072 + 2048 + col);
    const float* vb = vcache + (size_t)b * S_LEN * E_DIM;
    float* nvb = newv + (size_t)b * SEQ * E_DIM;

    __shared__ float w_s[NH][64];
    const float* wblk = wts + (size_t)(b * 64 + c) * (NH * 64);
    for (int idx = t; idx < NH * 64; idx += 256)
        w_s[idx >> 6][idx & 63] = wblk[idx];
    __syncthreads();

    float l = 0.f;
    f32x4 acc = (f32x4){0.f, 0.f, 0.f, 0.f};
    const bool clean = (((last >> 3) & 63) != c) && (c != 63);

    if (clean) {
        for (int i = 0; i < 8; ++i) {
            const int sb = 8 * c + 512 * i;
            #pragma unroll
            for (int g = 0; g < 8; g += 4) {
                f32x4 vv[4];
                #pragma unroll
                for (int u = 0; u < 4; ++u)
                    vv[u] = *(const f32x4*)(vb + (size_t)(sb + g + u) * E_DIM + col);
                #pragma unroll
                for (int u = 0; u < 4; ++u)
                    ntstore4(nvb + (size_t)(sb + g + u) * E_DIM + col, vv[u]);
                #pragma unroll
                for (int u = 0; u < 4; ++u) {
                    const float w = w_s[head][i * 8 + g + u];
                    l += w;
                    acc += vv[u] * w;
                }
            }
        }
    } else {
        for (int i = 0; i < 8; ++i) {
            #pragma unroll
            for (int u = 0; u < 8; ++u) {
                const int s = 8 * c + 512 * i + u;
                f32x4 vv;
                if (s == last) vv = vn4;
                else if (s < S_LEN) vv = *(const f32x4*)(vb + (size_t)s * E_DIM + col);
                else vv = (f32x4){0.f, 0.f, 0.f, 0.f};
                ntstore4(nvb + (size_t)s * E_DIM + col, vv);
                const float w = w_s[head][i * 8 + u];
                l += w;
                acc += vv * w;
            }
        }
    }

    const int pidx = (b * NH + head) * 64 + c;
    if (lig == 0) pl[pidx] = l;
    *(f32x4*)(pctx + (size_t)pidx * HD + lig * 4) = acc;
}

// -------- fused fallback (small workspace) --------
template <int CHUNK_T>
__global__ __launch_bounds__(256) void attn_fused_kernel(
    const float* __restrict__ kcache, const float* __restrict__ vcache,
    const float* __restrict__ mbias,
    const float* __restrict__ qkv, const int* __restrict__ lastbuf,
    float* __restrict__ newk, float* __restrict__ newv,
    float* __restrict__ pl, float* __restrict__ pctx) {
    constexpr int NCHUNK_T = SEQ / CHUNK_T;
    const int b = blockIdx.y;
    const int chunk = blockIdx.x;
    const int t = threadIdx.x;
    const int wave = t >> 6;
    const int lane = t & 63;
    const int head = wave * 4 + (lane >> 4);
    const int lig = lane & 15;
    const int col = head * HD + lig * 4;
    const int last = lastbuf[b];

    const f32x4 q4 = *(const f32x4*)(qkv + b * 3072 + col);
    const f32x4 kn4 = *(const f32x4*)(qkv + b * 3072 + 1024 + col);
    const f32x4 vn4 = *(const f32x4*)(qkv + b * 3072 + 2048 + col);
    const float* kb = kcache + (size_t)b * S_LEN * E_DIM;
    const float* vb = vcache + (size_t)b * S_LEN * E_DIM;
    float* nkb = newk + (size_t)b * SEQ * E_DIM;
    float* nvb = newv + (size_t)b * SEQ * E_DIM;
    const float* mbb = mbias + b * SEQ;

    float l = 0.f;
    f32x4 acc = (f32x4){0.f, 0.f, 0.f, 0.f};
    const int s0 = chunk * CHUNK_T;
    for (int r = 0; r < CHUNK_T; ++r) {
        const int s = s0 + r;
        f32x4 kk, vv;
        if (s == last) { kk = kn4; vv = vn4; }
        else if (s < S_LEN) {
            kk = *(const f32x4*)(kb + (size_t)s * E_DIM + col);
            vv = *(const f32x4*)(vb + (size_t)s * E_DIM + col);
        } else { kk = (f32x4){0.f, 0.f, 0.f, 0.f}; vv = kk; }
        ntstore4(nkb + (size_t)s * E_DIM + col, kk);
        ntstore4(nvb + (size_t)s * E_DIM + col, vv);
        float p = kk[0] * q4[0] + kk[1] * q4[1] + kk[2] * q4[2] + kk[3] * q4[3];
        p += __shfl_xor(p, 1);
        p += __shfl_xor(p, 2);
        p += __shfl_xor(p, 4);
        p += __shfl_xor(p, 8);
        const float w = __expf(fmaf(p, 0.125f, mbb[s]));
        l += w;
        acc += vv * w;
    }
    const int pidx = (b * NH + head) * NCHUNK_T + chunk;
    if (lig == 0) pl[pidx] = l;
    *(f32x4*)(pctx + (size_t)pidx * HD + lig * 4) = acc;
}

// -------- kernel 3: reduce chunk partials per (b,h) --------
__global__ __launch_bounds__(256) void reduce_kernel(const float* __restrict__ pl,
                                                     const float* __restrict__ pctx,
                                                     float* __restrict__ ctxout,
                                                     int nchunk) {
    const int gw = (blockIdx.x * blockDim.x + threadIdx.x) >> 6;
    const int lane = threadIdx.x & 63;
    if (gw >= BATCH * NH) return;
    float lacc = 0.f, cacc = 0.f;
    for (int c = 0; c < nchunk; ++c) {
        lacc += pl[gw * nchunk + c];
        cacc += pctx[(size_t)(gw * nchunk + c) * HD + lane];
    }
    ctxout[gw * HD + lane] = cacc / lacc;
}

// -------- kernel 4: out = ctx @ c_proj_w + c_proj_b, 4-way k-sliced --------
__global__ __launch_bounds__(256) void proj_kernel(const float* __restrict__ ctx,
                                                   const float* __restrict__ W,
                                                   const float* __restrict__ bias,
                                                   float* __restrict__ out) {
    const int b = blockIdx.y;
    const int jj = threadIdx.x & 63;
    const int j = blockIdx.x * 64 + jj;
    const int ksl = threadIdx.x >> 6;
    __shared__ float h[E_DIM];
    for (int i = threadIdx.x; i < E_DIM; i += 256) h[i] = ctx[b * E_DIM + i];
    __syncthreads();
    float acc = 0.f;
    const int k0 = ksl * 256;
    #pragma unroll 8
    for (int k = k0; k < k0 + 256; ++k) acc = fmaf(h[k], W[(size_t)k * E_DIM + j], acc);
    __shared__ float red[4][64];
    red[ksl][jj] = acc;
    __syncthreads();
    if (ksl == 0)
        out[b * E_DIM + j] = acc + red[1][jj] + red[2][jj] + red[3][jj] + bias[j];
}

extern "C" void kernel_launch(void* const* d_in, const int* in_sizes, int n_in,
                              void* d_out, int out_size, void* d_ws, size_t ws_size,
                              hipStream_t stream) {
    const float* hs      = (const float*)d_in[0];
    const float* kcache  = (const float*)d_in[1];
    const float* vcache  = (const float*)d_in[2];
    const int*   mask    = (const int*)d_in[3];
    const float* attn_w  = (const float*)d_in[4];
    const float* attn_b  = (const float*)d_in[5];
    const float* proj_w  = (const float*)d_in[6];
    const float* proj_b  = (const float*)d_in[7];
    const float* bias0   = (const float*)d_in[8];

    float* out0 = (float*)d_out;
    float* newk = out0 + (size_t)BATCH * E_DIM;
    float* newv = newk + (size_t)BATCH * SEQ * E_DIM;

    float* ws = (float*)d_ws;
    float* qkv    = ws;                       // 98304
    float* ctxbuf = qkv + 98304;              // 32768
    float* mbias  = ctxbuf + 32768;           // 131072

    const size_t base = 98304 + 32768 + 131072;
    const size_t need_split = (base + 2097152ull + 32768 + 2097152ull + 32) * 4;
    const bool use_split = ws_size >= need_split;

    if (use_split) {
        float* wts     = mbias + 131072;                      // 2097152
        float* pl      = wts + 2097152;                       // 32768
        float* pctx    = pl + 32768;                          // 2097152
        int*   lastbuf = (int*)(pctx + 2097152);

        prep_kernel<<<dim3(BATCH), dim3(256), 0, stream>>>(mask, bias0, lastbuf, mbias);
        qkv_kernel<<<dim3(48, BATCH), dim3(256), 0, stream>>>(hs, attn_w, attn_b, qkv);
        attn_k_kernel<<<dim3(64, BATCH), dim3(256), 0, stream>>>(
            kcache, mbias, qkv, lastbuf, newk, wts);
        attn_v_kernel<<<dim3(64, BATCH), dim3(256), 0, stream>>>(
            vcache, wts, qkv, lastbuf, newv, pl, pctx);
        reduce_kernel<<<dim3((BATCH * NH * 64 + 255) / 256), dim3(256), 0, stream>>>(
            pl, pctx, ctxbuf, 64);
        proj_kernel<<<dim3(16, BATCH), dim3(256), 0, stream>>>(ctxbuf, proj_w, proj_b, out0);
    } else {
        float* pl      = mbias + 131072;                      // 16384 (NCH=32)
        float* pctx    = pl + 16384;                          // 1048576
        int*   lastbuf = (int*)(pctx + 1048576);

        prep_kernel<<<dim3(BATCH), dim3(256), 0, stream>>>(mask, bias0, lastbuf, mbias);
        qkv_kernel<<<dim3(48, BATCH), dim3(256), 0, stream>>>(hs, attn_w, attn_b, qkv);
        attn_fused_kernel<128><<<dim3(32, BATCH), dim3(256), 0, stream>>>(
            kcache, vcache, mbias, qkv, lastbuf, newk, newv, pl, pctx);
        reduce_kernel<<<dim3((BATCH * NH * 64 + 255) / 256), dim3(256), 0, stream>>>(
            pl, pctx, ctxbuf, 32);
        proj_kernel<<<dim3(16, BATCH), dim3(256), 0, stream>>>(ctxbuf, proj_w, proj_b, out0);
    }
}